// Round 2
// baseline (4066.603 us; speedup 1.0000x reference)
//
#include <hip/hip_runtime.h>

#define N 8192
#define NITER 20
#define TOLF 1e-10f
#define TILE 2048   // columns per LDS-staged p tile

// ---------------- init: x=0, r=p0=RHS, RT0 = sum(RHS^2) ----------------
__global__ __launch_bounds__(256) void init_kernel(
    const float* __restrict__ RHS, float* __restrict__ x, float* __restrict__ r,
    float* __restrict__ p0, float* __restrict__ rt0) {
  int i = blockIdx.x * 256 + threadIdx.x;
  float v = RHS[i];
  x[i] = 0.0f;
  r[i] = v;
  p0[i] = v;
  float val = v * v;
  for (int off = 32; off > 0; off >>= 1) val += __shfl_down(val, off, 64);
  __shared__ float bs[4];
  int wave = threadIdx.x >> 6, lane = threadIdx.x & 63;
  if (lane == 0) bs[wave] = val;
  __syncthreads();
  if (threadIdx.x == 0) atomicAdd(rt0, bs[0] + bs[1] + bs[2] + bs[3]);
}

// ---------------- fused matvec ----------------
// Computes p_k = act ? r + beta*p_in : p_in ON THE FLY (staged per-tile in LDS,
// shared by 4 row-waves), Ap = M @ p_k, pAp reduction, writes p_k to p_out
// (ping-pong; each block owns columns [4b,4b+4)), and publishes RT[k].
__global__ __launch_bounds__(256, 8) void matvec_fused(
    const float* __restrict__ M, const float* __restrict__ r,
    const float* __restrict__ p_in, float* __restrict__ p_out,
    float* __restrict__ Ap,
    const float* __restrict__ rtPrev, const float* __restrict__ rnPrev,
    float* __restrict__ rtOut, float* __restrict__ pap, int first) {
  __shared__ float pt[TILE];
  __shared__ float bs[4];
  int tid = threadIdx.x;
  int wave = tid >> 6, lane = tid & 63;
  int b = blockIdx.x;
  int row = b * 4 + wave;

  bool act = true;
  float beta = 0.0f;
  if (!first) {
    float rtp = *rtPrev;
    float rnp = *rnPrev;
    act = rtp > TOLF;
    beta = act ? rnp / rtp : 0.0f;   // guard: no NaN when frozen
    if (b == 0 && tid == 0) *rtOut = act ? rnp : rtp;  // RT[k] for update1
  }

  // write this block's owned p_out columns [4b, 4b+4)
  if (tid == 0) {
    int c0 = b * 4;
    float4 rv = *(const float4*)(r + c0);
    float4 pv = *(const float4*)(p_in + c0);
    float4 o;
    o.x = act ? rv.x + beta * pv.x : pv.x;
    o.y = act ? rv.y + beta * pv.y : pv.y;
    o.z = act ? rv.z + beta * pv.z : pv.z;
    o.w = act ? rv.w + beta * pv.w : pv.w;
    *(float4*)(p_out + c0) = o;
  }

  const float* Mr = M + (size_t)row * N;
  float acc = 0.0f;
  for (int t = 0; t < N; t += TILE) {
    // ---- stage p_k tile into LDS (256 threads x 8 floats) ----
    {
      int c1 = t + tid * 4;
      float4 rv = *(const float4*)(r + c1);
      float4 pv = *(const float4*)(p_in + c1);
      float4 o;
      o.x = act ? rv.x + beta * pv.x : pv.x;
      o.y = act ? rv.y + beta * pv.y : pv.y;
      o.z = act ? rv.z + beta * pv.z : pv.z;
      o.w = act ? rv.w + beta * pv.w : pv.w;
      *(float4*)(pt + tid * 4) = o;
      int c2 = c1 + 1024;
      float4 rv2 = *(const float4*)(r + c2);
      float4 pv2 = *(const float4*)(p_in + c2);
      float4 o2;
      o2.x = act ? rv2.x + beta * pv2.x : pv2.x;
      o2.y = act ? rv2.y + beta * pv2.y : pv2.y;
      o2.z = act ? rv2.z + beta * pv2.z : pv2.z;
      o2.w = act ? rv2.w + beta * pv2.w : pv2.w;
      *(float4*)(pt + 1024 + tid * 4) = o2;
    }
    __syncthreads();
    // ---- each wave: its row segment against the LDS tile ----
#pragma unroll
    for (int j = 0; j < 8; ++j) {
      int c = j * 256 + lane * 4;
      float4 m  = *(const float4*)(Mr + t + c);
      float4 pv = *(const float4*)(pt + c);
      acc += m.x * pv.x + m.y * pv.y + m.z * pv.z + m.w * pv.w;
    }
    __syncthreads();
  }
  // wave reduce row sum
  for (int off = 32; off > 0; off >>= 1) acc += __shfl_down(acc, off, 64);
  if (lane == 0) {
    Ap[row] = acc;
    float pr = r[row], pi = p_in[row];
    float pvr = act ? pr + beta * pi : pi;
    bs[wave] = pvr * acc;
  }
  __syncthreads();
  if (tid == 0) atomicAdd(pap, bs[0] + bs[1] + bs[2] + bs[3]);
}

// ---------------- update1: alpha; x += alpha p; r -= alpha Ap; RN[k] = sum(rn^2)
__global__ __launch_bounds__(256) void update1_kernel(
    const float* __restrict__ Ap, const float* __restrict__ p,
    float* __restrict__ x, float* __restrict__ r,
    const float* __restrict__ rt, const float* __restrict__ pap,
    float* __restrict__ rn) {
  int i = blockIdx.x * 256 + threadIdx.x;
  float rtv = *rt;
  bool act = rtv > TOLF;
  float val = 0.0f;
  if (act) {
    float alpha = rtv / *pap;
    x[i] += alpha * p[i];
    float rv = r[i] - alpha * Ap[i];
    r[i] = rv;
    val = rv * rv;
  }
  for (int off = 32; off > 0; off >>= 1) val += __shfl_down(val, off, 64);
  __shared__ float bs[4];
  int wave = threadIdx.x >> 6, lane = threadIdx.x & 63;
  if (lane == 0) bs[wave] = val;
  __syncthreads();
  if (threadIdx.x == 0) atomicAdd(rn, bs[0] + bs[1] + bs[2] + bs[3]);
}

extern "C" void kernel_launch(void* const* d_in, const int* in_sizes, int n_in,
                              void* d_out, int out_size, void* d_ws, size_t ws_size,
                              hipStream_t stream) {
  const float* M   = (const float*)d_in[1];
  const float* RHS = (const float*)d_in[2];
  float* x = (float*)d_out;   // x lives in d_out; init zeroes it

  float* ws = (float*)d_ws;
  float* Ap = ws;             // N
  float* r  = ws + N;         // N
  float* p0 = ws + 2 * N;     // N
  float* p1 = ws + 3 * N;     // N
  float* sc = ws + 4 * N;
  float* RT    = sc;          // [0..NITER]          (21)
  float* RN    = sc + 21;     // [0..NITER], RN[20] stays 0 (zero slot for k=0)
  float* PAP   = sc + 42;     // [0..NITER-1]        (20)
  float* dummy = sc + 62;     // rtOut sink for k=0

  hipMemsetAsync(sc, 0, 63 * sizeof(float), stream);

  init_kernel<<<N / 256, 256, 0, stream>>>(RHS, x, r, p0, &RT[0]);

  float* pb[2] = {p0, p1};
  for (int k = 0; k < NITER; ++k) {
    matvec_fused<<<N / 4, 256, 0, stream>>>(
        M, r, pb[k % 2], pb[(k + 1) % 2], Ap,
        k ? &RT[k - 1] : &RT[0], k ? &RN[k - 1] : &RN[NITER],
        k ? &RT[k] : dummy, &PAP[k], k == 0 ? 1 : 0);
    update1_kernel<<<N / 256, 256, 0, stream>>>(
        Ap, pb[(k + 1) % 2], x, r, &RT[k], &PAP[k], &RN[k]);
  }
}

// Round 4
// 1359.928 us; speedup vs baseline: 2.9903x; 2.9903x over previous
//
#include <hip/hip_runtime.h>

#define N 8192
#define NITER 20
#define TOLF 1e-10f
#define STREAM_BLOCKS 256   // blocks 0..255 (rows 0..2047, 67 MB) use nontemporal M loads;
                            // remaining 201 MB of M is allowed to persist in the 256 MB LLC

typedef float floatx4 __attribute__((ext_vector_type(4)));

// ---------------- init: x=0, r=p=RHS, rt0 = sum(RHS^2) ----------------
__global__ __launch_bounds__(256) void init_kernel(
    const float* __restrict__ RHS, float* __restrict__ x, float* __restrict__ r,
    float* __restrict__ p, float* __restrict__ rt0) {
  int i = blockIdx.x * 256 + threadIdx.x;
  float v = RHS[i];
  x[i] = 0.0f;
  r[i] = v;
  p[i] = v;
  float val = v * v;
  for (int off = 32; off > 0; off >>= 1) val += __shfl_down(val, off, 64);
  __shared__ float bs[4];
  int wave = threadIdx.x >> 6, lane = threadIdx.x & 63;
  if (lane == 0) bs[wave] = val;
  __syncthreads();
  if (threadIdx.x == 0) atomicAdd(rt0, bs[0] + bs[1] + bs[2] + bs[3]);
}

// ---------------- matvec: Ap = M @ p, pAp += p.Ap ----------------
// 2 rows per wave, 8 rows per block, grid = N/8 = 1024 blocks.
// Barrier-free streaming; M loads nontemporal for the first STREAM_BLOCKS
// blocks so the remaining ~201 MB of M can stay resident in the LLC
// across the 20 iterations.
__device__ __forceinline__ floatx4 ld_nt(const float* a) {
  return __builtin_nontemporal_load((const floatx4*)a);
}
__device__ __forceinline__ floatx4 ld_n(const float* a) {
  return *(const floatx4*)a;
}

__global__ __launch_bounds__(256) void matvec_kernel(
    const float* __restrict__ M, const float* __restrict__ p,
    float* __restrict__ Ap, float* __restrict__ pAp) {
  int wave = threadIdx.x >> 6;
  int lane = threadIdx.x & 63;
  int row0 = blockIdx.x * 8 + wave * 2;
  const float* M0 = M + (size_t)row0 * N;
  const float* M1 = M0 + N;
  float acc0 = 0.0f, acc1 = 0.0f;

  if (blockIdx.x < STREAM_BLOCKS) {
#pragma unroll 4
    for (int c = lane * 4; c < N; c += 256) {
      floatx4 pv = ld_n(p + c);
      floatx4 m0 = ld_nt(M0 + c);
      floatx4 m1 = ld_nt(M1 + c);
      acc0 += m0.x * pv.x + m0.y * pv.y + m0.z * pv.z + m0.w * pv.w;
      acc1 += m1.x * pv.x + m1.y * pv.y + m1.z * pv.z + m1.w * pv.w;
    }
  } else {
#pragma unroll 4
    for (int c = lane * 4; c < N; c += 256) {
      floatx4 pv = ld_n(p + c);
      floatx4 m0 = ld_n(M0 + c);
      floatx4 m1 = ld_n(M1 + c);
      acc0 += m0.x * pv.x + m0.y * pv.y + m0.z * pv.z + m0.w * pv.w;
      acc1 += m1.x * pv.x + m1.y * pv.y + m1.z * pv.z + m1.w * pv.w;
    }
  }

  for (int off = 32; off > 0; off >>= 1) {
    acc0 += __shfl_down(acc0, off, 64);
    acc1 += __shfl_down(acc1, off, 64);
  }
  __shared__ float bs[4];
  if (lane == 0) {
    Ap[row0]     = acc0;
    Ap[row0 + 1] = acc1;
    bs[wave] = p[row0] * acc0 + p[row0 + 1] * acc1;
  }
  __syncthreads();
  if (threadIdx.x == 0) atomicAdd(pAp, bs[0] + bs[1] + bs[2] + bs[3]);
}

// ---------------- update1: alpha; x += alpha p; r -= alpha Ap; rn = sum(rnew^2)
__global__ __launch_bounds__(256) void update1_kernel(
    const float* __restrict__ Ap, const float* __restrict__ p,
    float* __restrict__ x, float* __restrict__ r,
    const float* __restrict__ rt, const float* __restrict__ pap,
    float* __restrict__ rn) {
  int i = blockIdx.x * 256 + threadIdx.x;
  float rtv = *rt;
  bool act = rtv > TOLF;
  float val = 0.0f;
  if (act) {
    float alpha = rtv / *pap;
    x[i] += alpha * p[i];
    float rv = r[i] - alpha * Ap[i];
    r[i] = rv;
    val = rv * rv;
  }
  for (int off = 32; off > 0; off >>= 1) val += __shfl_down(val, off, 64);
  __shared__ float bs[4];
  int wave = threadIdx.x >> 6, lane = threadIdx.x & 63;
  if (lane == 0) bs[wave] = val;
  __syncthreads();
  if (threadIdx.x == 0) atomicAdd(rn, bs[0] + bs[1] + bs[2] + bs[3]);
}

// ---------------- update2: beta; p = r + beta p; rt[k+1] = act ? rn : rt
__global__ __launch_bounds__(256) void update2_kernel(
    const float* __restrict__ r, float* __restrict__ p,
    const float* __restrict__ rt, const float* __restrict__ rn,
    float* __restrict__ rt_next) {
  int i = blockIdx.x * 256 + threadIdx.x;
  float rtv = *rt;
  float rnv = *rn;
  bool act = rtv > TOLF;
  if (act) {
    float beta = rnv / rtv;
    p[i] = r[i] + beta * p[i];
  }
  if (i == 0) *rt_next = act ? rnv : rtv;
}

extern "C" void kernel_launch(void* const* d_in, const int* in_sizes, int n_in,
                              void* d_out, int out_size, void* d_ws, size_t ws_size,
                              hipStream_t stream) {
  const float* M   = (const float*)d_in[1];
  const float* RHS = (const float*)d_in[2];
  float* x = (float*)d_out;      // x accumulates directly in d_out

  float* ws = (float*)d_ws;
  float* Ap = ws;                // N
  float* r  = ws + N;            // N
  float* p  = ws + 2 * N;        // N
  float* sc = ws + 3 * N;        // scalars
  float* RT  = sc;               // [0..NITER]   (21)
  float* PAP = sc + 21;          // [0..NITER-1] (20)
  float* RN  = sc + 41;          // [0..NITER-1] (20)

  (void)hipMemsetAsync(sc, 0, 61 * sizeof(float), stream);

  init_kernel<<<N / 256, 256, 0, stream>>>(RHS, x, r, p, &RT[0]);

  for (int k = 0; k < NITER; ++k) {
    matvec_kernel<<<N / 8, 256, 0, stream>>>(M, p, Ap, &PAP[k]);
    update1_kernel<<<N / 256, 256, 0, stream>>>(Ap, p, x, r, &RT[k], &PAP[k], &RN[k]);
    update2_kernel<<<N / 256, 256, 0, stream>>>(r, p, &RT[k], &RN[k], &RT[k + 1]);
  }
}

// Round 5
// 1105.888 us; speedup vs baseline: 3.6772x; 1.2297x over previous
//
#include <hip/hip_runtime.h>

#define N 8192
#define NITER 20
#define TOLF 1e-10f

typedef float floatx4 __attribute__((ext_vector_type(4)));
typedef unsigned int uintx4 __attribute__((ext_vector_type(4)));

__device__ __forceinline__ unsigned short f2bf_rne(float f) {
  unsigned int u = __float_as_uint(f);
  unsigned int r = u + 0x7fffu + ((u >> 16) & 1u);
  return (unsigned short)(r >> 16);
}
__device__ __forceinline__ float bflo(unsigned int u) { return __uint_as_float(u << 16); }
__device__ __forceinline__ float bfhi(unsigned int u) { return __uint_as_float(u & 0xffff0000u); }

// ---------------- cast: M fp32 -> bf16 (RNE), 8 elems/thread ----------------
__global__ __launch_bounds__(256) void cast_kernel(const float* __restrict__ M,
                                                   unsigned short* __restrict__ Mb) {
  size_t base = ((size_t)blockIdx.x * 256 + threadIdx.x) * 8;
  floatx4 a = *(const floatx4*)(M + base);
  floatx4 b = *(const floatx4*)(M + base + 4);
  unsigned int o0 = (unsigned int)f2bf_rne(a.x) | ((unsigned int)f2bf_rne(a.y) << 16);
  unsigned int o1 = (unsigned int)f2bf_rne(a.z) | ((unsigned int)f2bf_rne(a.w) << 16);
  unsigned int o2 = (unsigned int)f2bf_rne(b.x) | ((unsigned int)f2bf_rne(b.y) << 16);
  unsigned int o3 = (unsigned int)f2bf_rne(b.z) | ((unsigned int)f2bf_rne(b.w) << 16);
  uintx4 o = {o0, o1, o2, o3};
  *(uintx4*)(Mb + base) = o;
}

// ---------------- init: x=0, r=p=RHS, rt0 = sum(RHS^2) ----------------
__global__ __launch_bounds__(256) void init_kernel(
    const float* __restrict__ RHS, float* __restrict__ x, float* __restrict__ r,
    float* __restrict__ p, float* __restrict__ rt0) {
  int i = blockIdx.x * 256 + threadIdx.x;
  float v = RHS[i];
  x[i] = 0.0f;
  r[i] = v;
  p[i] = v;
  float val = v * v;
  for (int off = 32; off > 0; off >>= 1) val += __shfl_down(val, off, 64);
  __shared__ float bs[4];
  int wave = threadIdx.x >> 6, lane = threadIdx.x & 63;
  if (lane == 0) bs[wave] = val;
  __syncthreads();
  if (threadIdx.x == 0) atomicAdd(rt0, bs[0] + bs[1] + bs[2] + bs[3]);
}

// ---------------- matvec (bf16 M): Ap = Mb @ p, pAp += p.Ap ----------------
// 2 rows/wave, 8 rows/block, grid 1024. Lane i handles 8 consecutive cols.
__global__ __launch_bounds__(256) void matvec_bf16(
    const unsigned short* __restrict__ Mb, const float* __restrict__ p,
    float* __restrict__ Ap, float* __restrict__ pAp) {
  int wave = threadIdx.x >> 6;
  int lane = threadIdx.x & 63;
  int row0 = blockIdx.x * 8 + wave * 2;
  const unsigned short* M0 = Mb + (size_t)row0 * N;
  const unsigned short* M1 = M0 + N;
  float acc0 = 0.0f, acc1 = 0.0f;
#pragma unroll 4
  for (int c = lane * 8; c < N; c += 512) {
    uintx4 m0 = *(const uintx4*)(M0 + c);
    uintx4 m1 = *(const uintx4*)(M1 + c);
    floatx4 pa = *(const floatx4*)(p + c);
    floatx4 pb = *(const floatx4*)(p + c + 4);
    acc0 += bflo(m0.x) * pa.x + bfhi(m0.x) * pa.y
          + bflo(m0.y) * pa.z + bfhi(m0.y) * pa.w
          + bflo(m0.z) * pb.x + bfhi(m0.z) * pb.y
          + bflo(m0.w) * pb.z + bfhi(m0.w) * pb.w;
    acc1 += bflo(m1.x) * pa.x + bfhi(m1.x) * pa.y
          + bflo(m1.y) * pa.z + bfhi(m1.y) * pa.w
          + bflo(m1.z) * pb.x + bfhi(m1.z) * pb.y
          + bflo(m1.w) * pb.z + bfhi(m1.w) * pb.w;
  }
  for (int off = 32; off > 0; off >>= 1) {
    acc0 += __shfl_down(acc0, off, 64);
    acc1 += __shfl_down(acc1, off, 64);
  }
  __shared__ float bs[4];
  if (lane == 0) {
    Ap[row0]     = acc0;
    Ap[row0 + 1] = acc1;
    bs[wave] = p[row0] * acc0 + p[row0 + 1] * acc1;
  }
  __syncthreads();
  if (threadIdx.x == 0) atomicAdd(pAp, bs[0] + bs[1] + bs[2] + bs[3]);
}

// ---------------- fused update: x,r updates + rn reduce; last block does beta,p
// Deadlock-free: no spinning. p reads precede counter increment; last-block
// p writes follow the acquiring final increment (device-scope acq_rel).
__global__ __launch_bounds__(256) void update_fused(
    const float* __restrict__ Ap, float* __restrict__ p,
    float* __restrict__ x, float* __restrict__ r,
    const float* __restrict__ rt, const float* __restrict__ pap,
    float* __restrict__ rn, float* __restrict__ rt_next,
    int* __restrict__ counter) {
  int i = blockIdx.x * 256 + threadIdx.x;
  float rtv = *rt;
  bool act = rtv > TOLF;
  float val = 0.0f;
  if (act) {
    float alpha = rtv / *pap;
    x[i] += alpha * p[i];
    float rv = r[i] - alpha * Ap[i];
    r[i] = rv;
    val = rv * rv;
  }
  for (int off = 32; off > 0; off >>= 1) val += __shfl_down(val, off, 64);
  __shared__ float bs[4];
  __shared__ int tick;
  int wave = threadIdx.x >> 6, lane = threadIdx.x & 63;
  if (lane == 0) bs[wave] = val;
  __syncthreads();
  if (threadIdx.x == 0) {
    float S = bs[0] + bs[1] + bs[2] + bs[3];
    __hip_atomic_fetch_add(rn, S, __ATOMIC_RELAXED, __HIP_MEMORY_SCOPE_AGENT);
    tick = __hip_atomic_fetch_add(counter, 1, __ATOMIC_ACQ_REL, __HIP_MEMORY_SCOPE_AGENT);
  }
  __syncthreads();
  if (tick == (int)gridDim.x - 1) {
    float rnv = __hip_atomic_load(rn, __ATOMIC_RELAXED, __HIP_MEMORY_SCOPE_AGENT);
    if (threadIdx.x == 0) *rt_next = act ? rnv : rtv;
    if (act) {
      float beta = rnv / rtv;
      for (int j = threadIdx.x; j < N; j += 256)
        p[j] = r[j] + beta * p[j];
    }
  }
}

extern "C" void kernel_launch(void* const* d_in, const int* in_sizes, int n_in,
                              void* d_out, int out_size, void* d_ws, size_t ws_size,
                              hipStream_t stream) {
  const float* M   = (const float*)d_in[1];
  const float* RHS = (const float*)d_in[2];
  float* x = (float*)d_out;          // x accumulates directly in d_out

  char* ws = (char*)d_ws;
  unsigned short* Mb = (unsigned short*)ws;              // N*N bf16 = 134 MB
  float* Ap = (float*)(ws + (size_t)N * N * 2);          // N
  float* r  = Ap + N;                                    // N
  float* p  = r + N;                                     // N
  float* sc = p + N;                                     // scalars
  float* RT  = sc;               // [0..NITER]   (21)
  float* PAP = sc + 21;          // 20
  float* RN  = sc + 41;          // 20
  int*   CNT = (int*)(sc + 61);  // 20

  (void)hipMemsetAsync(sc, 0, 81 * sizeof(float), stream);

  cast_kernel<<<(N / 8) * (N / 256), 256, 0, stream>>>(M, Mb);
  init_kernel<<<N / 256, 256, 0, stream>>>(RHS, x, r, p, &RT[0]);

  for (int k = 0; k < NITER; ++k) {
    matvec_bf16<<<N / 8, 256, 0, stream>>>(Mb, p, Ap, &PAP[k]);
    update_fused<<<N / 256, 256, 0, stream>>>(Ap, p, x, r, &RT[k], &PAP[k],
                                              &RN[k], &RT[k + 1], &CNT[k]);
  }
}